// Round 8
// baseline (90.967 us; speedup 1.0000x reference)
//
#include <hip/hip_runtime.h>
#include <cstdint>
#include <cstddef>

typedef unsigned long long u64;

// 1-instruction rotate
#if defined(__HIP_DEVICE_COMPILE__)
#define ROTL(x, r) __builtin_amdgcn_alignbit((x), (x), 32 - (r))
#else
#define ROTL(x, r) (((x) << (r)) | ((x) >> (32 - (r))))
#endif

// guaranteed-native log2 (v_log_f32)
__device__ __forceinline__ float fast_log2(float x){
  float r;
  asm("v_log_f32 %0, %1" : "=v"(r) : "v"(x));
  return r;
}

// ---------------- threefry2x32: two interleaved independent chains ------
__device__ __forceinline__ void tf2x32x2(uint32_t k0, uint32_t k1,
                                         uint32_t& a0, uint32_t& a1,
                                         uint32_t& b0, uint32_t& b1){
  const uint32_t k2 = k0 ^ k1 ^ 0x1BD11BDAu;
  a0 += k0; b0 += k0; a1 += k1; b1 += k1;
#define TFR2(r) { a0 += a1; b0 += b1; a1 = ROTL(a1, r); b1 = ROTL(b1, r); a1 ^= a0; b1 ^= b0; }
  TFR2(13) TFR2(15) TFR2(26) TFR2(6)
  a0 += k1; b0 += k1; a1 += k2 + 1u; b1 += k2 + 1u;
  TFR2(17) TFR2(29) TFR2(16) TFR2(24)
  a0 += k2; b0 += k2; a1 += k0 + 2u; b1 += k0 + 2u;
  TFR2(13) TFR2(15) TFR2(26) TFR2(6)
  a0 += k0; b0 += k0; a1 += k1 + 3u; b1 += k1 + 3u;
  TFR2(17) TFR2(29) TFR2(16) TFR2(24)
  a0 += k1; b0 += k1; a1 += k2 + 4u; b1 += k2 + 4u;
  TFR2(13) TFR2(15) TFR2(26) TFR2(6)
  a0 += k2; b0 += k2; a1 += k0 + 5u; b1 += k0 + 5u;
#undef TFR2
}

constexpr void tf2x32_h(uint32_t k0, uint32_t k1, uint32_t& x0, uint32_t& x1){
  const uint32_t k2 = k0 ^ k1 ^ 0x1BD11BDAu;
  x0 += k0; x1 += k1;
#define TFR(r) { x0 += x1; x1 = ((x1<<(r))|(x1>>(32-(r)))); x1 ^= x0; }
  TFR(13) TFR(15) TFR(26) TFR(6)
  x0 += k1; x1 += k2 + 1u;
  TFR(17) TFR(29) TFR(16) TFR(24)
  x0 += k2; x1 += k0 + 2u;
  TFR(13) TFR(15) TFR(26) TFR(6)
  x0 += k0; x1 += k1 + 3u;
  TFR(17) TFR(29) TFR(16) TFR(24)
  x0 += k1; x1 += k2 + 4u;
  TFR(13) TFR(15) TFR(26) TFR(6)
  x0 += k2; x1 += k0 + 5u;
#undef TFR
}

struct Keys { uint32_t k0[10]; uint32_t k1[10]; };
constexpr Keys make_keys(){
  Keys K{};
  for (int s = 0; s < 10; ++s){
    uint32_t x0 = 0u, x1 = (uint32_t)s;
    tf2x32_h(0u, 42u, x0, x1);
    K.k0[s] = x0; K.k1[s] = x1;
  }
  return K;
}
__constant__ constexpr Keys KEYS = make_keys();

__device__ __forceinline__ float crlogf(float x){
  return (float)log((double)x);   // reference-exact (proven R1-R7 absmax=0)
}

// fast gumbel-race score: (-log2 u) / p, negative-domain tricks
__device__ __forceinline__ float qscore(uint32_t m, float rp){
  const float u  = fmaxf((float)m * 0x1p-23f, 1.17549435e-38f);
  const float l2 = fast_log2(u);
  const float e = 1.0f - u;                        // Sterbenz-exact for u>=0.5
  float t = -0.14426950408889635f;                 // -(1/10)/ln2
  t = fmaf(t, e, -0.16029944898766261f);
  t = fmaf(t, e, -0.18033688011112044f);
  t = fmaf(t, e, -0.20609929155556624f);
  t = fmaf(t, e, -0.24044917348149392f);
  t = fmaf(t, e, -0.28853900817779270f);
  t = fmaf(t, e, -0.36067376022224088f);
  t = fmaf(t, e, -0.48089834696298781f);
  t = fmaf(t, e, -0.72134752044448169f);
  t = fmaf(t, e, -1.4426950408889634f);
  const float sp = e * t;
  const float sv = (m >= 0x600000u) ? sp : l2;
  return -sv * rp;
}

__device__ __forceinline__ int fast_pick(const float q[4], bool& guard){
  const float m01 = fminf(q[0], q[1]), M01 = fmaxf(q[0], q[1]);
  const float m23 = fminf(q[2], q[3]), M23 = fmaxf(q[2], q[3]);
  const float b1 = fminf(m01, m23);
  const float b2 = fminf(fmaxf(m01, m23), fminf(M01, M23));
  int bc = 3;
  bc = (q[2] == b1) ? 2 : bc;
  bc = (q[1] == b1) ? 1 : bc;
  bc = (q[0] == b1) ? 0 : bc;
  guard = (b2 - b1) < 2e-5f * b2;
  return bc;
}

__device__ __forceinline__ int exact_pick(const uint32_t mv[4], const float p[4]){
  float best = -3.0e38f; int bc = 0;
#pragma unroll
  for (int c = 0; c < 4; ++c){
    const uint32_t m = mv[c];
    const float u = m ? (float)m * 0x1p-23f : 1.17549435e-38f;
    const float w = -crlogf(u);
    const float g = -crlogf(w);
    const float sc = g + crlogf(p[c]);
    if (sc > best){ best = sc; bc = c; }
  }
  return bc;
}

// ---------------- kernel 1: sampling (2 pixels/thread, ILP x2) ----------
__global__ __launch_bounds__(256) void k_sample(const float* __restrict__ prob,
                                                u64* __restrict__ planes)
{
  const int T    = blockIdx.x * 256 + threadIdx.x;  // 0..262143
  const int lane = threadIdx.x & 63;
  const int n     = T >> 15;
  const int chunk = (T & 32767) >> 6;               // 128-pixel chunk, 0..511
  const int pixA  = (chunk << 7) | lane;
  const int pixB  = pixA + 64;

  uint32_t jA[4], jB[4];
  float pA[4], rpA[4], pB[4], rpB[4];
#pragma unroll
  for (int c = 0; c < 4; ++c){
    jA[c] = (uint32_t)((((n<<2)|c) << 16) | pixA);
    jB[c] = jA[c] + 64u;
    pA[c] = prob[jA[c]]; rpA[c] = __builtin_amdgcn_rcpf(pA[c]);
    pB[c] = prob[jB[c]]; rpB[c] = __builtin_amdgcn_rcpf(pB[c]);
  }

#pragma unroll 1
  for (int s = 0; s < 10; ++s){
    const uint32_t k0 = KEYS.k0[s];
    const uint32_t k1 = KEYS.k1[s];

    uint32_t mA[4], mB[4];
    float qA[4], qB[4];
#pragma unroll
    for (int c = 0; c < 4; ++c){
      uint32_t a0 = 0u, a1 = jA[c];
      uint32_t b0 = 0u, b1 = jB[c];
      tf2x32x2(k0, k1, a0, a1, b0, b1);
      mA[c] = (a0 ^ a1) >> 9;
      mB[c] = (b0 ^ b1) >> 9;
      qA[c] = qscore(mA[c], rpA[c]);
      qB[c] = qscore(mB[c], rpB[c]);
    }
    bool gA, gB;
    int bcA = fast_pick(qA, gA);
    int bcB = fast_pick(qB, gB);
    if (gA) bcA = exact_pick(mA, pA);   // rare, bit-identical reference path
    if (gB) bcB = exact_pick(mB, pB);

    const int wbase = ((n * 10 + s) << 10) | (chunk << 1);
    const u64 wa0 = __ballot(bcA & 1);
    const u64 wa1 = __ballot(bcA & 2);
    const u64 wb0 = __ballot(bcB & 1);
    const u64 wb1 = __ballot(bcB & 2);
    if (lane == 0){
      planes[(size_t)wbase*2 + 0]     = wa0;
      planes[(size_t)wbase*2 + 1]     = wa1;
      planes[(size_t)(wbase+1)*2 + 0] = wb0;
      planes[(size_t)(wbase+1)*2 + 1] = wb1;
    }
  }
}

// ---------------- kernel 2: fill-bitmap (1024 thr, SWAR seed) -----------
__device__ __forceinline__ void add256(const u64 a[4], const u64 b[4], u64 o[4]){
  u64 c = 0;
#pragma unroll
  for (int w = 0; w < 4; ++w){
    const u64 t = a[w] + c;
    const u64 c1 = (t < c) ? 1ull : 0ull;
    const u64 s = t + b[w];
    const u64 c2 = (s < t) ? 1ull : 0ull;
    o[w] = s;
    c = c1 | c2;
  }
}

__device__ __forceinline__ void runfill(const u64 m[4], const u64 s[4], u64 o[4]){
  u64 A[4];
  add256(m, s, A);
  u64 rm[4], rs[4], RA[4];
#pragma unroll
  for (int w = 0; w < 4; ++w){ rm[w] = __brevll(m[3-w]); rs[w] = __brevll(s[3-w]); }
  add256(rm, rs, RA);
#pragma unroll
  for (int w = 0; w < 4; ++w){
    const u64 up  = (A[w] ^ m[w]) & m[w];
    const u64 rdn = (RA[3-w] ^ rm[3-w]) & rm[3-w];
    o[w] = s[w] | up | __brevll(rdn);
  }
}

__global__ __launch_bounds__(1024) void k_reward(const u64* __restrict__ planes,
                                                 u64* __restrict__ fillB)
{
  const int b   = blockIdx.x;        // 0..239
  const int ns  = b / 3;
  const int cls = (b % 3) + 1;
  const int t   = threadIdx.x;       // 0..1023
  const int r   = t >> 2;            // row
  const int wd  = t & 3;             // word

  __shared__ u64 fgS[256*5];
  __shared__ u64 v0S[256*6], v1S[256*6], v2S[256*6];
  __shared__ u64 fillS[258*5];
  __shared__ u64 bestKey;
  __shared__ int flag;
  __shared__ int flags[2];

  const u64 c0 = (u64)(cls & 1);
  const u64 c1 = (u64)((cls >> 1) & 1);
  const int idxp = (ns << 10) | (r << 2) | wd;
  const ulonglong2 pw = ((const ulonglong2*)planes)[idxp];
  const u64 fg = (c0 ? pw.x : ~pw.x) & (c1 ? pw.y : ~pw.y);
  fgS[r*5 + wd] = fg;
  if (t == 0){ flag = 0; bestKey = 0ull; flags[0] = 0; flags[1] = 0; }
  if (t < 2){
    const int gr = (t == 0) ? 0 : 257;
#pragma unroll
    for (int w = 0; w < 5; ++w) fillS[gr*5 + w] = 0ull;
  }
  __syncthreads();
  if (fg) flag = 1;                  // benign race
  __syncthreads();
  if (!flag) return;

  // ---- vertical 5-sum (bit-sliced, 3 planes) ----
  u64 a0, a1, a2, a3, a4;
  { const int rm2 = r-2, rm1 = r-1, rp1 = r+1, rp2 = r+2;
    a0 = (rm2 >= 0)  ? fgS[rm2*5 + wd] : 0ull;
    a1 = (rm1 >= 0)  ? fgS[rm1*5 + wd] : 0ull;
    a2 = fg;
    a3 = (rp1 < 256) ? fgS[rp1*5 + wd] : 0ull;
    a4 = (rp2 < 256) ? fgS[rp2*5 + wd] : 0ull; }
  u64 v0, v1, v2;
  { const u64 t0 = a0^a1, ca = a0&a1;
    const u64 t1 = t0^a2, cb = t0&a2;
    const u64 t2 = t1^a3, cc = t1&a3;
    v0 = t2^a4;  const u64 cd = t2&a4;
    const u64 w0 = ca^cb, d0 = ca&cb;
    const u64 w1 = cc^cd, d1 = cc&cd;
    v1 = w0^w1;  const u64 d2 = w0&w1;
    v2 = d0|d1|d2; }
  v0S[r*6 + wd + 1] = v0;  v1S[r*6 + wd + 1] = v1;  v2S[r*6 + wd + 1] = v2;
  if (wd == 0){ v0S[r*6] = 0ull; v1S[r*6] = 0ull; v2S[r*6] = 0ull; }
  if (wd == 3){ v0S[r*6+5] = 0ull; v1S[r*6+5] = 0ull; v2S[r*6+5] = 0ull; }
  __syncthreads();

  // ---- horizontal 5-sum -> 5 planes h0..h4 ----
  u64 h0, h1, h2, h3, h4;
  {
    const u64 L0 = v0S[r*6+wd], M0 = v0, R0 = v0S[r*6+wd+2];
    const u64 L1 = v1S[r*6+wd], M1 = v1, R1 = v1S[r*6+wd+2];
    const u64 L2 = v2S[r*6+wd], M2 = v2, R2 = v2S[r*6+wd+2];
#define SHP(M,L,R,dx) ((dx) > 0 ? (((M) >> (dx)) | ((R) << (64-(dx)))) \
                                : (((M) << (-(dx))) | ((L) >> (64+(dx)))))
    const u64 pA0 = SHP(M0,L0,R0,-2), pA1 = SHP(M1,L1,R1,-2), pA2 = SHP(M2,L2,R2,-2);
    const u64 pB0 = SHP(M0,L0,R0,-1), pB1 = SHP(M1,L1,R1,-1), pB2 = SHP(M2,L2,R2,-1);
    const u64 pD0 = SHP(M0,L0,R0, 1), pD1 = SHP(M1,L1,R1, 1), pD2 = SHP(M2,L2,R2, 1);
    const u64 pE0 = SHP(M0,L0,R0, 2), pE1 = SHP(M1,L1,R1, 2), pE2 = SHP(M2,L2,R2, 2);
#undef SHP
    u64 A0, A1, A2, A3;
    { u64 c = pA0 & pB0; A0 = pA0 ^ pB0;
      u64 x = pA1 ^ pB1; A1 = x ^ c; c = (pA1 & pB1) | (c & x);
      u64 y = pA2 ^ pB2; A2 = y ^ c; c = (pA2 & pB2) | (c & y);
      A3 = c; }
    u64 B0, B1, B2, B3;
    { u64 c = pD0 & pE0; B0 = pD0 ^ pE0;
      u64 x = pD1 ^ pE1; B1 = x ^ c; c = (pD1 & pE1) | (c & x);
      u64 y = pD2 ^ pE2; B2 = y ^ c; c = (pD2 & pE2) | (c & y);
      B3 = c; }
    u64 C0, C1, C2, C3, C4;
    { u64 c = A0 & B0; C0 = A0 ^ B0;
      u64 x = A1 ^ B1; C1 = x ^ c; c = (A1 & B1) | (c & x);
      u64 y = A2 ^ B2; C2 = y ^ c; c = (A2 & B2) | (c & y);
      u64 z = A3 ^ B3; C3 = z ^ c; c = (A3 & B3) | (c & z);
      C4 = c; }
    { u64 c = C0 & M0; h0 = C0 ^ M0;
      u64 x = C1 ^ M1; h1 = x ^ c; c = (C1 & M1) | (c & x);
      u64 y = C2 ^ M2; h2 = y ^ c; c = (C2 & M2) | (c & y);
      h3 = C3 ^ c; c = C3 & c;
      h4 = C4 ^ c; }
  }

  // ---- masked bit-sliced max + first-index argmax ----
  u64 myKey = 0ull;
  if (fg){
    u64 cand = fg; unsigned maxv = 0u;
    u64 tt;
    tt = cand & h4; if (tt){ cand = tt; maxv |= 16u; }
    tt = cand & h3; if (tt){ cand = tt; maxv |= 8u; }
    tt = cand & h2; if (tt){ cand = tt; maxv |= 4u; }
    tt = cand & h1; if (tt){ cand = tt; maxv |= 2u; }
    tt = cand & h0; if (tt){ cand = tt; maxv |= 1u; }
    const int bit = __builtin_ctzll(cand);
    const unsigned idx = (unsigned)((r << 8) | (wd << 6) | bit);
    myKey = ((u64)maxv << 32) | (u64)(0xFFFFFFFFu - idx);
  }
#pragma unroll
  for (int off = 32; off; off >>= 1){
    const u64 o = (u64)__shfl_xor((long long)myKey, off, 64);
    if (o > myKey) myKey = o;
  }
  if ((t & 63) == 0) atomicMax(&bestKey, myKey);
  __syncthreads();
  const int seedIdx = (int)(0xFFFFFFFFu - (unsigned)(bestKey & 0xFFFFFFFFull));
  const int srow = seedIdx >> 8, scol = seedIdx & 255;

  // ---- scanline flood fill ----
  u64 f[4] = {0ull,0ull,0ull,0ull};
  u64 g[4] = {0ull,0ull,0ull,0ull};
  if (t < 256){
#pragma unroll
    for (int w = 0; w < 4; ++w) g[w] = fgS[t*5 + w];
    if (t == srow) f[scol >> 6] = 1ull << (scol & 63);
#pragma unroll
    for (int w = 0; w < 4; ++w) fillS[(t+1)*5 + w] = f[w];
  }
  __syncthreads();

  int it = 0;
  for (;;){
    bool ch = false;
    u64 nf[4];
    if (t < 256){
      u64 U[4], S[4];
#pragma unroll
      for (int w = 0; w < 4; ++w)
        U[w] = fillS[t*5 + w] | fillS[(t+1)*5 + w] | fillS[(t+2)*5 + w];
      S[0] = U[0] | (U[0]<<1) | (U[0]>>1) | (U[1]<<63);
      S[1] = U[1] | (U[1]<<1) | (U[1]>>1) | (U[0]>>63) | (U[2]<<63);
      S[2] = U[2] | (U[2]<<1) | (U[2]>>1) | (U[1]>>63) | (U[3]<<63);
      S[3] = U[3] | (U[3]<<1) | (U[3]>>1) | (U[2]>>63);
#pragma unroll
      for (int w = 0; w < 4; ++w) S[w] &= g[w];
      runfill(g, S, nf);
#pragma unroll
      for (int w = 0; w < 4; ++w){ ch |= (nf[w] != f[w]); f[w] = nf[w]; }
    }
    __syncthreads();
    if (t < 256){
#pragma unroll
      for (int w = 0; w < 4; ++w) fillS[(t+1)*5 + w] = f[w];
    }
    if (ch) flags[it & 1] = 1;
    if (t == 0) flags[(it + 1) & 1] = 0;
    __syncthreads();
    if (!flags[it & 1]) break;
    ++it;
  }

  if (t < 256){
    const int nsc = ns*3 + (cls - 1);
    u64* fb = fillB + (((size_t)nsc) << 10) + (t << 2);
#pragma unroll
    for (int w = 0; w < 4; ++w) fb[w] = f[w];
  }
}

// ---------------- kernel 3: output write --------------------------------
__global__ __launch_bounds__(256) void k_write(const u64* __restrict__ planes,
                                               const u64* __restrict__ fillB,
                                               const float* __restrict__ prob,
                                               float* __restrict__ out)
{
  const int T = blockIdx.x * 256 + threadIdx.x;
  const int lane = T & 63;
#pragma unroll
  for (int i = 0; i < 10; ++i){
    const int g  = i * 524288 + T;
    const int wi = g >> 6;
    const u64 pw0 = planes[(size_t)wi*2 + 0];
    const u64 pw1 = planes[(size_t)wi*2 + 1];
    const int ns = g >> 16;
    const int n  = ns / 10;
    const int pp = g & 0xFFFF;
    const int fwi = pp >> 6;
    const u64 f1 = fillB[(((size_t)(ns*3 + 0)) << 10) | fwi];
    const u64 f2 = fillB[(((size_t)(ns*3 + 1)) << 10) | fwi];
    const u64 f3 = fillB[(((size_t)(ns*3 + 2)) << 10) | fwi];
    const float pa = prob[(size_t)((((n<<2)|1) << 16) | pp)];
    const float pb = prob[(size_t)((((n<<2)|2) << 16) | pp)];
    const float pc = prob[(size_t)((((n<<2)|3) << 16) | pp)];
    const int cls = (int)((pw0 >> lane) & 1ull) | (((int)((pw1 >> lane) & 1ull)) << 1);
    const u64   fw = (cls == 1) ? f1 : ((cls == 2) ? f2 : f3);
    const float p  = (cls == 1) ? pa : ((cls == 2) ? pb : pc);
    const uint32_t sgn = ((uint32_t)((fw >> lane) & 1ull)) << 31;
    float o = __uint_as_float(__float_as_uint(p) ^ sgn);
    if (cls == 0) o = 0.0f;
    out[g] = o;
  }
}

extern "C" void kernel_launch(void* const* d_in, const int* in_sizes, int n_in,
                              void* d_out, int out_size, void* d_ws, size_t ws_size,
                              hipStream_t stream)
{
  const float* prob = (const float*)d_in[0];
  float* out = (float*)d_out;
  u64* planes = (u64*)d_ws;            // 1.31 MB
  u64* fillB  = planes + 163840;       // 1.97 MB

  k_sample<<<1024, 256, 0, stream>>>(prob, planes);
  k_reward<<<240, 1024, 0, stream>>>(planes, fillB);
  k_write <<<2048, 256, 0, stream>>>(planes, fillB, prob, out);
}